// Round 1
// baseline (1241.665 us; speedup 1.0000x reference)
//
#include <hip/hip_runtime.h>
#include <math.h>

#define H 12
#define S 1024
#define D 128
#define NROWS (H * S) // 12288

// ---- workspace layout (float offsets) ----
#define QP_R_OFF   0ULL
#define QP_I_OFF   3145728ULL
#define KP_R_OFF   6291456ULL
#define KP_I_OFF   7864320ULL
#define VP_R_OFF   9437184ULL
#define VP_I_OFF   11010048ULL
#define G_R_OFF    12582912ULL
#define G_I_OFF    14155776ULL
#define ACAT_R_OFF 15728640ULL
#define ACAT_I_OFF 18874368ULL
#define LAM_OFF    22020096ULL
#define SC_OFF     22020160ULL
#define SC_PER_HEAD 2097152ULL // 2*1024*1024 floats

// ============================================================
// lambda = sigmoid(exp(sum lq1*lk1) - exp(sum lq2*lk2) + LAMBDA_INIT)
// ============================================================
__global__ void lam_kernel(const float* __restrict__ lq1, const float* __restrict__ lk1,
                           const float* __restrict__ lq2, const float* __restrict__ lk2,
                           float* __restrict__ lam_out)
{
    int t = threadIdx.x; // 128 threads
    float p1 = lq1[t] * lk1[t];
    float p2 = lq2[t] * lk2[t];
    #pragma unroll
    for (int off = 32; off; off >>= 1) {
        p1 += __shfl_xor(p1, off);
        p2 += __shfl_xor(p2, off);
    }
    __shared__ float s1[2], s2[2];
    if ((t & 63) == 0) { s1[t >> 6] = p1; s2[t >> 6] = p2; }
    __syncthreads();
    if (t == 0) {
        float l1 = expf(s1[0] + s1[1]);
        float l2 = expf(s2[0] + s2[1]);
        float x = l1 - l2 + 0.3555090675909693f; // 0.8 - 0.6*exp(-0.3)
        lam_out[0] = 1.0f / (1.0f + expf(-x));
    }
}

// ============================================================
// Generic complex linear:  out = (xr + i xi) @ (wr + i wi)^T + (br + i bi)
// x: [NROWS x 128], w: [M x 128], out: [NROWS x M]
// optional PE add: out_r += per[row*128 + (col&127)] (and pei for imag)
// 64x64 tile, BK=32, 4x4 per thread.
// ============================================================
__global__ __launch_bounds__(256) void clin_kernel(
    const float* __restrict__ xr, const float* __restrict__ xi,
    const float* __restrict__ wr, const float* __restrict__ wi,
    const float* __restrict__ br, const float* __restrict__ bi,
    const float* __restrict__ per, const float* __restrict__ pei,
    float* __restrict__ outr, float* __restrict__ outi, int M)
{
    __shared__ __align__(16) float Ar[32][68], Ai[32][68], Br_s[32][68], Bi_s[32][68];
    const int t = threadIdx.x;
    const int row0 = blockIdx.x * 64;
    const int col0 = blockIdx.y * 64;
    const int tr = t >> 4, tc = t & 15;
    float accr[4][4] = {{0}}, acci[4][4] = {{0}};

    for (int k0 = 0; k0 < 128; k0 += 32) {
        #pragma unroll
        for (int it = 0; it < 8; ++it) {
            int idx = it * 256 + t;
            int r = idx >> 5, kk = idx & 31;
            Ar[kk][r]   = xr[(size_t)(row0 + r) * 128 + k0 + kk];
            Ai[kk][r]   = xi[(size_t)(row0 + r) * 128 + k0 + kk];
            Br_s[kk][r] = wr[(size_t)(col0 + r) * 128 + k0 + kk];
            Bi_s[kk][r] = wi[(size_t)(col0 + r) * 128 + k0 + kk];
        }
        __syncthreads();
        #pragma unroll 8
        for (int kk = 0; kk < 32; ++kk) {
            float4 v;
            v = *(const float4*)&Ar[kk][tr * 4];   float axr[4] = {v.x, v.y, v.z, v.w};
            v = *(const float4*)&Ai[kk][tr * 4];   float axi[4] = {v.x, v.y, v.z, v.w};
            v = *(const float4*)&Br_s[kk][tc * 4]; float bxr[4] = {v.x, v.y, v.z, v.w};
            v = *(const float4*)&Bi_s[kk][tc * 4]; float bxi[4] = {v.x, v.y, v.z, v.w};
            #pragma unroll
            for (int i = 0; i < 4; ++i)
                #pragma unroll
                for (int j = 0; j < 4; ++j) {
                    accr[i][j] = fmaf(axr[i],  bxr[j], accr[i][j]);
                    accr[i][j] = fmaf(-axi[i], bxi[j], accr[i][j]);
                    acci[i][j] = fmaf(axr[i],  bxi[j], acci[i][j]);
                    acci[i][j] = fmaf(axi[i],  bxr[j], acci[i][j]);
                }
        }
        __syncthreads();
    }
    #pragma unroll
    for (int i = 0; i < 4; ++i) {
        int r = row0 + tr * 4 + i;
        #pragma unroll
        for (int j = 0; j < 4; ++j) {
            int c = col0 + tc * 4 + j;
            float vr_ = accr[i][j] + br[c];
            float vi_ = acci[i][j] + bi[c];
            if (per) {
                vr_ += per[(size_t)r * 128 + (c & 127)];
                vi_ += pei[(size_t)r * 128 + (c & 127)];
            }
            outr[(size_t)r * M + c] = vr_;
            outi[(size_t)r * M + c] = vi_;
        }
    }
}

// ============================================================
// Scores: for head h, q-tile x, key-tile y compute
//   s_r = q.r·k.r + q.i·k.i ; s_i = q.i·k.r - q.r·k.i  (for q1 and q2)
//   mag = sqrt(s_r^2 + s_i^2 + 1e-8) * D^-0.5
// writes mag1, mag2 into scores[(hh*2+m)*S + q][k]
// ============================================================
__global__ __launch_bounds__(256) void score_kernel(
    const float* __restrict__ qp_r, const float* __restrict__ qp_i,
    const float* __restrict__ kp_r, const float* __restrict__ kp_i,
    float* __restrict__ scores, int h0)
{
    __shared__ __align__(16) float Q1r[32][68], Q1i[32][68], Q2r[32][68], Q2i[32][68],
                                   Kr[32][68], Ki[32][68];
    const int t = threadIdx.x;
    const int hh = blockIdx.z;
    const int h = h0 + hh;
    const int q0 = blockIdx.x * 64;
    const int c0 = blockIdx.y * 64;
    const int tr = t >> 4, tc = t & 15;
    float sr1[4][4] = {{0}}, si1[4][4] = {{0}}, sr2[4][4] = {{0}}, si2[4][4] = {{0}};

    for (int k0 = 0; k0 < 128; k0 += 32) {
        #pragma unroll
        for (int it = 0; it < 8; ++it) {
            int idx = it * 256 + t;
            int r = idx >> 5, kk = idx & 31;
            size_t qbase = ((size_t)(h * S + q0 + r)) * 256 + k0 + kk;
            Q1r[kk][r] = qp_r[qbase];
            Q2r[kk][r] = qp_r[qbase + 128];
            Q1i[kk][r] = qp_i[qbase];
            Q2i[kk][r] = qp_i[qbase + 128];
            size_t kbase = ((size_t)(h * S + c0 + r)) * 128 + k0 + kk;
            Kr[kk][r] = kp_r[kbase];
            Ki[kk][r] = kp_i[kbase];
        }
        __syncthreads();
        #pragma unroll 4
        for (int kk = 0; kk < 32; ++kk) {
            float4 v;
            v = *(const float4*)&Q1r[kk][tr * 4]; float q1r[4] = {v.x, v.y, v.z, v.w};
            v = *(const float4*)&Q1i[kk][tr * 4]; float q1i[4] = {v.x, v.y, v.z, v.w};
            v = *(const float4*)&Q2r[kk][tr * 4]; float q2r[4] = {v.x, v.y, v.z, v.w};
            v = *(const float4*)&Q2i[kk][tr * 4]; float q2i[4] = {v.x, v.y, v.z, v.w};
            v = *(const float4*)&Kr[kk][tc * 4];  float kr[4]  = {v.x, v.y, v.z, v.w};
            v = *(const float4*)&Ki[kk][tc * 4];  float ki[4]  = {v.x, v.y, v.z, v.w};
            #pragma unroll
            for (int i = 0; i < 4; ++i)
                #pragma unroll
                for (int j = 0; j < 4; ++j) {
                    sr1[i][j] = fmaf(q1r[i], kr[j], sr1[i][j]);
                    sr1[i][j] = fmaf(q1i[i], ki[j], sr1[i][j]);
                    si1[i][j] = fmaf(q1i[i], kr[j], si1[i][j]);
                    si1[i][j] = fmaf(-q1r[i], ki[j], si1[i][j]);
                    sr2[i][j] = fmaf(q2r[i], kr[j], sr2[i][j]);
                    sr2[i][j] = fmaf(q2i[i], ki[j], sr2[i][j]);
                    si2[i][j] = fmaf(q2i[i], kr[j], si2[i][j]);
                    si2[i][j] = fmaf(-q2r[i], ki[j], si2[i][j]);
                }
        }
        __syncthreads();
    }
    const float scale = 0.08838834764831845f; // 128^-0.5
    #pragma unroll
    for (int i = 0; i < 4; ++i) {
        float st1[4], st2[4];
        #pragma unroll
        for (int j = 0; j < 4; ++j) {
            st1[j] = sqrtf(fmaf(sr1[i][j], sr1[i][j], fmaf(si1[i][j], si1[i][j], 1e-8f))) * scale;
            st2[j] = sqrtf(fmaf(sr2[i][j], sr2[i][j], fmaf(si2[i][j], si2[i][j], 1e-8f))) * scale;
        }
        int q = q0 + tr * 4 + i;
        size_t b1 = (((size_t)hh * 2 + 0) * S + q) * S + c0 + tc * 4;
        size_t b2 = (((size_t)hh * 2 + 1) * S + q) * S + c0 + tc * 4;
        *(float4*)&scores[b1] = *(const float4*)st1;
        *(float4*)&scores[b2] = *(const float4*)st2;
    }
}

// ============================================================
// Row softmax over 1024 (in place). One block per row.
// ============================================================
__global__ __launch_bounds__(256) void softmax_kernel(float* __restrict__ scores)
{
    float* row = scores + (size_t)blockIdx.x * S;
    int t = threadIdx.x;
    float4 v = reinterpret_cast<float4*>(row)[t];
    float m = fmaxf(fmaxf(v.x, v.y), fmaxf(v.z, v.w));
    #pragma unroll
    for (int off = 32; off; off >>= 1) m = fmaxf(m, __shfl_xor(m, off));
    __shared__ float redm[4], reds[4];
    int w = t >> 6;
    if ((t & 63) == 0) redm[w] = m;
    __syncthreads();
    m = fmaxf(fmaxf(redm[0], redm[1]), fmaxf(redm[2], redm[3]));
    float e0 = __expf(v.x - m), e1 = __expf(v.y - m), e2 = __expf(v.z - m), e3 = __expf(v.w - m);
    float s = e0 + e1 + e2 + e3;
    #pragma unroll
    for (int off = 32; off; off >>= 1) s += __shfl_xor(s, off);
    if ((t & 63) == 0) reds[w] = s;
    __syncthreads();
    s = reds[0] + reds[1] + reds[2] + reds[3];
    float inv = 1.0f / s;
    v.x = e0 * inv; v.y = e1 * inv; v.z = e2 * inv; v.w = e3 * inv;
    reinterpret_cast<float4*>(row)[t] = v;
}

// ============================================================
// AV: a1 = w1 @ vp, a2 = w2 @ vp (complex v). Writes acat[row][0:128]=a1,
// acat[row][128:256]=a2 (r and i planes).
// ============================================================
__global__ __launch_bounds__(256) void av_kernel(
    const float* __restrict__ scores, const float* __restrict__ vp_r, const float* __restrict__ vp_i,
    float* __restrict__ acat_r, float* __restrict__ acat_i, int h0)
{
    __shared__ __align__(16) float W1[32][68], W2[32][68], Vr[32][68], Vi[32][68];
    const int t = threadIdx.x;
    const int hh = blockIdx.z, h = h0 + hh;
    const int q0 = blockIdx.x * 64;
    const int d0 = blockIdx.y * 64;
    const int tr = t >> 4, tc = t & 15;
    float a1r[4][4] = {{0}}, a1i[4][4] = {{0}}, a2r[4][4] = {{0}}, a2i[4][4] = {{0}};

    for (int k0 = 0; k0 < S; k0 += 32) {
        #pragma unroll
        for (int it = 0; it < 8; ++it) {
            int idx = it * 256 + t;
            {
                int r = idx >> 5, kk = idx & 31;
                W1[kk][r] = scores[(((size_t)hh * 2 + 0) * S + q0 + r) * S + k0 + kk];
                W2[kk][r] = scores[(((size_t)hh * 2 + 1) * S + q0 + r) * S + k0 + kk];
            }
            {
                int kk = idx >> 6, dd = idx & 63;
                Vr[kk][dd] = vp_r[((size_t)(h * S + k0 + kk)) * 128 + d0 + dd];
                Vi[kk][dd] = vp_i[((size_t)(h * S + k0 + kk)) * 128 + d0 + dd];
            }
        }
        __syncthreads();
        #pragma unroll 8
        for (int kk = 0; kk < 32; ++kk) {
            float4 v;
            v = *(const float4*)&W1[kk][tr * 4]; float w1[4] = {v.x, v.y, v.z, v.w};
            v = *(const float4*)&W2[kk][tr * 4]; float w2[4] = {v.x, v.y, v.z, v.w};
            v = *(const float4*)&Vr[kk][tc * 4]; float vr[4] = {v.x, v.y, v.z, v.w};
            v = *(const float4*)&Vi[kk][tc * 4]; float vi[4] = {v.x, v.y, v.z, v.w};
            #pragma unroll
            for (int i = 0; i < 4; ++i)
                #pragma unroll
                for (int j = 0; j < 4; ++j) {
                    a1r[i][j] = fmaf(w1[i], vr[j], a1r[i][j]);
                    a1i[i][j] = fmaf(w1[i], vi[j], a1i[i][j]);
                    a2r[i][j] = fmaf(w2[i], vr[j], a2r[i][j]);
                    a2i[i][j] = fmaf(w2[i], vi[j], a2i[i][j]);
                }
        }
        __syncthreads();
    }
    #pragma unroll
    for (int i = 0; i < 4; ++i) {
        size_t row = (size_t)(h * S + q0 + tr * 4 + i);
        int c = d0 + tc * 4;
        float4 o;
        o.x = a1r[i][0]; o.y = a1r[i][1]; o.z = a1r[i][2]; o.w = a1r[i][3];
        *(float4*)&acat_r[row * 256 + c] = o;
        o.x = a2r[i][0]; o.y = a2r[i][1]; o.z = a2r[i][2]; o.w = a2r[i][3];
        *(float4*)&acat_r[row * 256 + 128 + c] = o;
        o.x = a1i[i][0]; o.y = a1i[i][1]; o.z = a1i[i][2]; o.w = a1i[i][3];
        *(float4*)&acat_i[row * 256 + c] = o;
        o.x = a2i[i][0]; o.y = a2i[i][1]; o.z = a2i[i][2]; o.w = a2i[i][3];
        *(float4*)&acat_i[row * 256 + 128 + c] = o;
    }
}

// ============================================================
// RMS over 256 complex elems + sub_w scale + (a1 - lam*a2) + complex gate.
// Reads g (gate proj), writes gated result in place into g_r/g_i.
// ============================================================
__global__ __launch_bounds__(256) void rmsgate_kernel(
    const float* __restrict__ acat_r, const float* __restrict__ acat_i,
    const float* __restrict__ sub_w, const float* __restrict__ lam_ptr,
    float* __restrict__ g_r, float* __restrict__ g_i)
{
    int row = blockIdx.x;
    int t = threadIdx.x;
    float ar = acat_r[(size_t)row * 256 + t];
    float ai = acat_i[(size_t)row * 256 + t];
    float ss = fmaf(ar, ar, ai * ai);
    #pragma unroll
    for (int off = 32; off; off >>= 1) ss += __shfl_xor(ss, off);
    __shared__ float red[4];
    if ((t & 63) == 0) red[t >> 6] = ss;
    __syncthreads();
    float total = red[0] + red[1] + red[2] + red[3];
    float inv_rms = 1.0f / sqrtf(total * (1.0f / 256.0f) + 1e-5f);
    float sw = sub_w[t];
    __shared__ float Cr[256], Ci[256];
    Cr[t] = ar * inv_rms * sw;
    Ci[t] = ai * inv_rms * sw;
    __syncthreads();
    if (t < 128) {
        float lam = lam_ptr[0];
        float o_r = Cr[t] - lam * Cr[t + 128];
        float o_i = Ci[t] - lam * Ci[t + 128];
        float gr = g_r[(size_t)row * 128 + t];
        float gi = g_i[(size_t)row * 128 + t];
        g_r[(size_t)row * 128 + t] = gr * o_r - gi * o_i;
        g_i[(size_t)row * 128 + t] = gr * o_i + gi * o_r;
    }
}

// ============================================================
extern "C" void kernel_launch(void* const* d_in, const int* in_sizes, int n_in,
                              void* d_out, int out_size, void* d_ws, size_t ws_size,
                              hipStream_t stream)
{
    (void)in_sizes; (void)n_in; (void)out_size;
    const float* q_r    = (const float*)d_in[0];
    const float* q_i    = (const float*)d_in[1];
    const float* k_r    = (const float*)d_in[2];
    const float* k_i    = (const float*)d_in[3];
    const float* v_r    = (const float*)d_in[4];
    const float* v_i    = (const float*)d_in[5];
    const float* pe_q_r = (const float*)d_in[6];
    const float* pe_q_i = (const float*)d_in[7];
    const float* pe_k_r = (const float*)d_in[8];
    const float* pe_k_i = (const float*)d_in[9];
    const float* qw_r   = (const float*)d_in[10];
    const float* qw_i   = (const float*)d_in[11];
    const float* qb_r   = (const float*)d_in[12];
    const float* qb_i   = (const float*)d_in[13];
    const float* kw_r   = (const float*)d_in[14];
    const float* kw_i   = (const float*)d_in[15];
    const float* kb_r   = (const float*)d_in[16];
    const float* kb_i   = (const float*)d_in[17];
    const float* vw_r   = (const float*)d_in[18];
    const float* vw_i   = (const float*)d_in[19];
    const float* vb_r   = (const float*)d_in[20];
    const float* vb_i   = (const float*)d_in[21];
    const float* gw_r   = (const float*)d_in[22];
    const float* gw_i   = (const float*)d_in[23];
    const float* gb_r   = (const float*)d_in[24];
    const float* gb_i   = (const float*)d_in[25];
    const float* ow_r   = (const float*)d_in[26];
    const float* ow_i   = (const float*)d_in[27];
    const float* ob_r   = (const float*)d_in[28];
    const float* ob_i   = (const float*)d_in[29];
    const float* lq1    = (const float*)d_in[30];
    const float* lk1    = (const float*)d_in[31];
    const float* lq2    = (const float*)d_in[32];
    const float* lk2    = (const float*)d_in[33];
    const float* sub_w  = (const float*)d_in[34];

    float* ws = (float*)d_ws;
    float* qp_r   = ws + QP_R_OFF;
    float* qp_i   = ws + QP_I_OFF;
    float* kp_r   = ws + KP_R_OFF;
    float* kp_i   = ws + KP_I_OFF;
    float* vp_r   = ws + VP_R_OFF;
    float* vp_i   = ws + VP_I_OFF;
    float* g_r    = ws + G_R_OFF;
    float* g_i    = ws + G_I_OFF;
    float* acat_r = ws + ACAT_R_OFF;
    float* acat_i = ws + ACAT_I_OFF;
    float* lam    = ws + LAM_OFF;
    float* scores = ws + SC_OFF;

    float* out_r = (float*)d_out;
    float* out_i = out_r + (size_t)NROWS * D;

    // head-chunking by available workspace (depends only on ws_size -> graph-safe)
    size_t ws_f = ws_size / 4;
    int nh_chunk = 1;
    if (ws_f > SC_OFF + SC_PER_HEAD) {
        size_t fit = (ws_f - SC_OFF) / SC_PER_HEAD;
        nh_chunk = (int)(fit > 12 ? 12 : fit);
        if (nh_chunk < 1) nh_chunk = 1;
    }

    lam_kernel<<<1, 128, 0, stream>>>(lq1, lk1, lq2, lk2, lam);

    // projections
    clin_kernel<<<dim3(192, 4), 256, 0, stream>>>(q_r, q_i, qw_r, qw_i, qb_r, qb_i,
                                                  pe_q_r, pe_q_i, qp_r, qp_i, 256);
    clin_kernel<<<dim3(192, 2), 256, 0, stream>>>(k_r, k_i, kw_r, kw_i, kb_r, kb_i,
                                                  pe_k_r, pe_k_i, kp_r, kp_i, 128);
    clin_kernel<<<dim3(192, 2), 256, 0, stream>>>(v_r, v_i, vw_r, vw_i, vb_r, vb_i,
                                                  nullptr, nullptr, vp_r, vp_i, 128);
    clin_kernel<<<dim3(192, 2), 256, 0, stream>>>(q_r, q_i, gw_r, gw_i, gb_r, gb_i,
                                                  nullptr, nullptr, g_r, g_i, 128);

    // attention, head-chunked through the scores workspace
    for (int h0 = 0; h0 < H; h0 += nh_chunk) {
        int nhh = (H - h0 < nh_chunk) ? (H - h0) : nh_chunk;
        score_kernel<<<dim3(16, 16, nhh), 256, 0, stream>>>(qp_r, qp_i, kp_r, kp_i, scores, h0);
        softmax_kernel<<<nhh * 2 * S, 256, 0, stream>>>(scores);
        av_kernel<<<dim3(16, 2, nhh), 256, 0, stream>>>(scores, vp_r, vp_i, acat_r, acat_i, h0);
    }

    // RMS + sub_w + lambda combine + complex gate (in place into g)
    rmsgate_kernel<<<NROWS, 256, 0, stream>>>(acat_r, acat_i, sub_w, lam, g_r, g_i);

    // output projection -> d_out (out_r then out_i)
    clin_kernel<<<dim3(192, 2), 256, 0, stream>>>(g_r, g_i, ow_r, ow_i, ob_r, ob_i,
                                                  nullptr, nullptr, out_r, out_i, 128);
}

// Round 3
// 370.423 us; speedup vs baseline: 3.3520x; 3.3520x over previous
//
#include <hip/hip_runtime.h>
#include <math.h>

#define H 12
#define S 1024
#define D 128
#define NROWS (H * S) // 12288

typedef __attribute__((ext_vector_type(8))) _Float16 f16x8; // 8 fp16 in 4 VGPRs
typedef __attribute__((ext_vector_type(4))) float f32x4;

__device__ __forceinline__ short f2h(float f) { // RNE float->fp16, bits as short
    _Float16 h = (_Float16)f;
    return __builtin_bit_cast(short, h);
}
__device__ __forceinline__ float h2f(short s) {
    return (float)__builtin_bit_cast(_Float16, s);
}
__device__ __forceinline__ short4 neg4(short4 v) { // fp16 sign flip
    v.x ^= (short)0x8000; v.y ^= (short)0x8000;
    v.z ^= (short)0x8000; v.w ^= (short)0x8000;
    return v;
}

// ---- workspace layout (BYTE offsets) ----
// qp fp16 [12288][256] r/i ; kp,vp fp16 [12288][128] r/i ; g fp32 [12288][128] r/i
// acat fp32 [12288][256] r/i ; lam ; then per-chunk: fp32 scores + fp16 weights
#define WS_QP_R   0ULL
#define WS_QP_I   6291456ULL
#define WS_KP_R   12582912ULL
#define WS_KP_I   15728640ULL
#define WS_VP_R   18874368ULL
#define WS_VP_I   22020096ULL
#define WS_G_R    25165824ULL
#define WS_G_I    31457280ULL
#define WS_ACAT_R 37748736ULL
#define WS_ACAT_I 50331648ULL
#define WS_LAM    62914560ULL
#define WS_SC     62914816ULL
#define SC32_PER_HEAD 8388608ULL // 2*1024*1024*4B
#define W16_PER_HEAD  4194304ULL // 2*1024*1024*2B

// ============================================================
__global__ void lam_kernel(const float* __restrict__ lq1, const float* __restrict__ lk1,
                           const float* __restrict__ lq2, const float* __restrict__ lk2,
                           float* __restrict__ lam_out)
{
    int t = threadIdx.x; // 128 threads
    float p1 = lq1[t] * lk1[t];
    float p2 = lq2[t] * lk2[t];
    #pragma unroll
    for (int off = 32; off; off >>= 1) {
        p1 += __shfl_xor(p1, off);
        p2 += __shfl_xor(p2, off);
    }
    __shared__ float s1[2], s2[2];
    if ((t & 63) == 0) { s1[t >> 6] = p1; s2[t >> 6] = p2; }
    __syncthreads();
    if (t == 0) {
        float l1 = expf(s1[0] + s1[1]);
        float l2 = expf(s2[0] + s2[1]);
        float x = l1 - l2 + 0.3555090675909693f; // 0.8 - 0.6*exp(-0.3)
        lam_out[0] = 1.0f / (1.0f + expf(-x));
    }
}

// ============================================================
// Complex linear via fp16 MFMA, K-concat over 256 virtual K:
//   out_r = [xr,xi] . [wr,-wi]^T ; out_i = [xr,xi] . [wi,wr]^T
// x fp32 [NROWS][128], w fp32 [M][128]. out fp16 or fp32 [NROWS][M].
// Optional PE add (per/pei fp32 [NROWS][128], col&127).
// Block: 256 thr (4 waves 2x2), tile 64x64, K-chunk 64.
// ============================================================
template <bool F16OUT>
__global__ __launch_bounds__(256) void clin_mfma(
    const float* __restrict__ xr, const float* __restrict__ xi,
    const float* __restrict__ wr, const float* __restrict__ wi,
    const float* __restrict__ br, const float* __restrict__ bi,
    const float* __restrict__ per, const float* __restrict__ pei,
    void* __restrict__ outr_, void* __restrict__ outi_, int M)
{
    __shared__ short As[64 * 72], Brs[64 * 72], Bis[64 * 72];
    const int t = threadIdx.x;
    const int row0 = blockIdx.x * 64, col0 = blockIdx.y * 64;
    const int lane = t & 63, wid = t >> 6;
    const int wm = (wid >> 1) * 32, wn = (wid & 1) * 32;
    const int fm = lane & 15, fq = lane >> 4;
    f32x4 zero4 = {0.f, 0.f, 0.f, 0.f};
    f32x4 accr[2][2], acci[2][2];
    #pragma unroll
    for (int i = 0; i < 2; ++i)
        #pragma unroll
        for (int j = 0; j < 2; ++j) { accr[i][j] = zero4; acci[i][j] = zero4; }

    for (int c = 0; c < 4; ++c) {
        const bool hi = (c >= 2);
        const int kb = (c & 1) * 64;
        const float* Asrc = hi ? xi : xr;
        const float* Brsrc = hi ? wi : wr;
        const float* Bisrc = hi ? wr : wi;
        const float bsign = hi ? -1.0f : 1.0f;
        __syncthreads();
        #pragma unroll
        for (int i = 0; i < 4; ++i) {
            int lin = i * 256 + t;
            int r = lin >> 4;
            int k4 = (lin & 15) * 4;
            float4 va = *(const float4*)&Asrc[(size_t)(row0 + r) * 128 + kb + k4];
            *(short4*)&As[r * 72 + k4] = make_short4(f2h(va.x), f2h(va.y), f2h(va.z), f2h(va.w));
            float4 vr = *(const float4*)&Brsrc[(size_t)(col0 + r) * 128 + kb + k4];
            *(short4*)&Brs[r * 72 + k4] = make_short4(f2h(bsign * vr.x), f2h(bsign * vr.y),
                                                      f2h(bsign * vr.z), f2h(bsign * vr.w));
            float4 vi = *(const float4*)&Bisrc[(size_t)(col0 + r) * 128 + kb + k4];
            *(short4*)&Bis[r * 72 + k4] = make_short4(f2h(vi.x), f2h(vi.y), f2h(vi.z), f2h(vi.w));
        }
        __syncthreads();
        #pragma unroll
        for (int ks = 0; ks < 64; ks += 32) {
            f16x8 a[2], bfr[2], bfi[2];
            #pragma unroll
            for (int i = 0; i < 2; ++i) {
                a[i]   = *(const f16x8*)&As[(wm + i * 16 + fm) * 72 + ks + fq * 8];
                bfr[i] = *(const f16x8*)&Brs[(wn + i * 16 + fm) * 72 + ks + fq * 8];
                bfi[i] = *(const f16x8*)&Bis[(wn + i * 16 + fm) * 72 + ks + fq * 8];
            }
            #pragma unroll
            for (int i = 0; i < 2; ++i)
                #pragma unroll
                for (int j = 0; j < 2; ++j) {
                    accr[i][j] = __builtin_amdgcn_mfma_f32_16x16x32_f16(a[i], bfr[j], accr[i][j], 0, 0, 0);
                    acci[i][j] = __builtin_amdgcn_mfma_f32_16x16x32_f16(a[i], bfi[j], acci[i][j], 0, 0, 0);
                }
        }
    }
    #pragma unroll
    for (int i = 0; i < 2; ++i)
        #pragma unroll
        for (int j = 0; j < 2; ++j) {
            int colc = col0 + wn + j * 16 + fm;
            float bbr = br[colc], bbi = bi[colc];
            #pragma unroll
            for (int reg = 0; reg < 4; ++reg) {
                int rr = row0 + wm + i * 16 + fq * 4 + reg;
                float o_r = accr[i][j][reg] + bbr;
                float o_i = acci[i][j][reg] + bbi;
                if (per) {
                    o_r += per[(size_t)rr * 128 + (colc & 127)];
                    o_i += pei[(size_t)rr * 128 + (colc & 127)];
                }
                if (F16OUT) {
                    ((short*)outr_)[(size_t)rr * M + colc] = f2h(o_r);
                    ((short*)outi_)[(size_t)rr * M + colc] = f2h(o_i);
                } else {
                    ((float*)outr_)[(size_t)rr * M + colc] = o_r;
                    ((float*)outi_)[(size_t)rr * M + colc] = o_i;
                }
            }
        }
}

// ============================================================
// Scores via fp16 MFMA. K-concat (K=256):
//  sr = [qr,qi].[kr,ki]  si = [qi,-qr].[kr,ki]  (per map 1,2)
// mag = sqrt(sr^2+si^2+1e-8)*D^-.5 -> fp32 sc32[(hh*2+m)*S+q][k]
// ============================================================
__global__ __launch_bounds__(256) void score_mfma(
    const short* __restrict__ qp_r, const short* __restrict__ qp_i,
    const short* __restrict__ kp_r, const short* __restrict__ kp_i,
    float* __restrict__ sc32, int h0)
{
    __shared__ short A1[64 * 72], A2[64 * 72], A3[64 * 72], A4[64 * 72], Bk[64 * 72];
    const int t = threadIdx.x;
    const int hh = blockIdx.z, h = h0 + hh;
    const int q0 = blockIdx.x * 64, c0 = blockIdx.y * 64;
    const int lane = t & 63, wid = t >> 6;
    const int wm = (wid >> 1) * 32, wn = (wid & 1) * 32;
    const int fm = lane & 15, fq = lane >> 4;
    f32x4 zero4 = {0.f, 0.f, 0.f, 0.f};
    f32x4 sr1[2][2], si1[2][2], sr2[2][2], si2[2][2];
    #pragma unroll
    for (int i = 0; i < 2; ++i)
        #pragma unroll
        for (int j = 0; j < 2; ++j) { sr1[i][j] = zero4; si1[i][j] = zero4; sr2[i][j] = zero4; si2[i][j] = zero4; }

    for (int c = 0; c < 4; ++c) {
        const bool hi = (c >= 2);
        const int kb = (c & 1) * 64;
        const short* s1 = hi ? qp_i : qp_r; // sr A-src
        const short* s2 = hi ? qp_r : qp_i; // si A-src (neg when hi)
        const short* sb = hi ? kp_i : kp_r;
        __syncthreads();
        #pragma unroll
        for (int i = 0; i < 4; ++i) {
            int lin = i * 256 + t;
            int r = lin >> 4, k4 = (lin & 15) * 4;
            size_t qb = (size_t)(h * S + q0 + r) * 256 + kb + k4;
            short4 v;
            v = *(const short4*)&s1[qb];                        *(short4*)&A1[r * 72 + k4] = v;
            v = *(const short4*)&s2[qb];       if (hi) v = neg4(v); *(short4*)&A2[r * 72 + k4] = v;
            v = *(const short4*)&s1[qb + 128];                  *(short4*)&A3[r * 72 + k4] = v;
            v = *(const short4*)&s2[qb + 128]; if (hi) v = neg4(v); *(short4*)&A4[r * 72 + k4] = v;
            size_t kbse = (size_t)(h * S + c0 + r) * 128 + kb + k4;
            v = *(const short4*)&sb[kbse];                      *(short4*)&Bk[r * 72 + k4] = v;
        }
        __syncthreads();
        #pragma unroll
        for (int ks = 0; ks < 64; ks += 32) {
            f16x8 b[2];
            #pragma unroll
            for (int j = 0; j < 2; ++j)
                b[j] = *(const f16x8*)&Bk[(wn + j * 16 + fm) * 72 + ks + fq * 8];
            #pragma unroll
            for (int i = 0; i < 2; ++i) {
                int arow = (wm + i * 16 + fm) * 72 + ks + fq * 8;
                f16x8 a1 = *(const f16x8*)&A1[arow];
                f16x8 a2 = *(const f16x8*)&A2[arow];
                f16x8 a3 = *(const f16x8*)&A3[arow];
                f16x8 a4 = *(const f16x8*)&A4[arow];
                #pragma unroll
                for (int j = 0; j < 2; ++j) {
                    sr1[i][j] = __builtin_amdgcn_mfma_f32_16x16x32_f16(a1, b[j], sr1[i][j], 0, 0, 0);
                    si1[i][j] = __builtin_amdgcn_mfma_f32_16x16x32_f16(a2, b[j], si1[i][j], 0, 0, 0);
                    sr2[i][j] = __builtin_amdgcn_mfma_f32_16x16x32_f16(a3, b[j], sr2[i][j], 0, 0, 0);
                    si2[i][j] = __builtin_amdgcn_mfma_f32_16x16x32_f16(a4, b[j], si2[i][j], 0, 0, 0);
                }
            }
        }
    }
    const float scale = 0.08838834764831845f;
    #pragma unroll
    for (int i = 0; i < 2; ++i)
        #pragma unroll
        for (int j = 0; j < 2; ++j) {
            int kcol = c0 + wn + j * 16 + fm;
            #pragma unroll
            for (int reg = 0; reg < 4; ++reg) {
                int q = q0 + wm + i * 16 + fq * 4 + reg;
                float r1 = sr1[i][j][reg], I1 = si1[i][j][reg];
                float r2 = sr2[i][j][reg], I2 = si2[i][j][reg];
                float m1 = sqrtf(fmaf(r1, r1, fmaf(I1, I1, 1e-8f))) * scale;
                float m2 = sqrtf(fmaf(r2, r2, fmaf(I2, I2, 1e-8f))) * scale;
                sc32[(((size_t)hh * 2 + 0) * S + q) * S + kcol] = m1;
                sc32[(((size_t)hh * 2 + 1) * S + q) * S + kcol] = m2;
            }
        }
}

// ============================================================
// Row softmax over 1024: fp32 in, fp16 out. One block/row.
// ============================================================
__global__ __launch_bounds__(256) void softmax_f32_f16(const float* __restrict__ sc32,
                                                       short* __restrict__ w16)
{
    const float* row = sc32 + (size_t)blockIdx.x * S;
    short* orow = w16 + (size_t)blockIdx.x * S;
    int t = threadIdx.x;
    float4 v = ((const float4*)row)[t];
    float m = fmaxf(fmaxf(v.x, v.y), fmaxf(v.z, v.w));
    #pragma unroll
    for (int off = 32; off; off >>= 1) m = fmaxf(m, __shfl_xor(m, off));
    __shared__ float redm[4], reds[4];
    int w = t >> 6;
    if ((t & 63) == 0) redm[w] = m;
    __syncthreads();
    m = fmaxf(fmaxf(redm[0], redm[1]), fmaxf(redm[2], redm[3]));
    float e0 = __expf(v.x - m), e1 = __expf(v.y - m), e2 = __expf(v.z - m), e3 = __expf(v.w - m);
    float ssum = e0 + e1 + e2 + e3;
    #pragma unroll
    for (int off = 32; off; off >>= 1) ssum += __shfl_xor(ssum, off);
    if ((t & 63) == 0) reds[w] = ssum;
    __syncthreads();
    ssum = reds[0] + reds[1] + reds[2] + reds[3];
    float inv = 1.0f / ssum;
    short4 o;
    o.x = f2h(e0 * inv); o.y = f2h(e1 * inv); o.z = f2h(e2 * inv); o.w = f2h(e3 * inv);
    ((short4*)orow)[t] = o;
}

// ============================================================
// AV via fp16 MFMA: a{1,2}{r,i}[q][d] = sum_k w{1,2}[q][k] v{r,i}[k][d]
// V transposed into LDS at staging. Writes acat fp32 [row][256].
// ============================================================
__global__ __launch_bounds__(256) void av_mfma(
    const short* __restrict__ w16, const short* __restrict__ vp_r, const short* __restrict__ vp_i,
    float* __restrict__ acat_r, float* __restrict__ acat_i, int h0)
{
    __shared__ short W1[64 * 72], W2[64 * 72], Vr[64 * 72], Vi[64 * 72];
    const int t = threadIdx.x;
    const int hh = blockIdx.z, h = h0 + hh;
    const int q0 = blockIdx.x * 64, d0 = blockIdx.y * 64;
    const int lane = t & 63, wid = t >> 6;
    const int wm = (wid >> 1) * 32, wn = (wid & 1) * 32;
    const int fm = lane & 15, fq = lane >> 4;
    f32x4 zero4 = {0.f, 0.f, 0.f, 0.f};
    f32x4 a1r[2][2], a1i[2][2], a2r[2][2], a2i[2][2];
    #pragma unroll
    for (int i = 0; i < 2; ++i)
        #pragma unroll
        for (int j = 0; j < 2; ++j) { a1r[i][j] = zero4; a1i[i][j] = zero4; a2r[i][j] = zero4; a2i[i][j] = zero4; }

    for (int k0 = 0; k0 < S; k0 += 64) {
        __syncthreads();
        #pragma unroll
        for (int i = 0; i < 4; ++i) {
            int lin = i * 256 + t;
            int r = lin >> 4, k4 = (lin & 15) * 4;
            *(short4*)&W1[r * 72 + k4] = *(const short4*)&w16[(((size_t)hh * 2 + 0) * S + q0 + r) * S + k0 + k4];
            *(short4*)&W2[r * 72 + k4] = *(const short4*)&w16[(((size_t)hh * 2 + 1) * S + q0 + r) * S + k0 + k4];
            // V transpose: r is kk (0..63), k4 is d-offset
            short4 vr4 = *(const short4*)&vp_r[(size_t)(h * S + k0 + r) * 128 + d0 + k4];
            short4 vi4 = *(const short4*)&vp_i[(size_t)(h * S + k0 + r) * 128 + d0 + k4];
            Vr[(k4 + 0) * 72 + r] = vr4.x; Vr[(k4 + 1) * 72 + r] = vr4.y;
            Vr[(k4 + 2) * 72 + r] = vr4.z; Vr[(k4 + 3) * 72 + r] = vr4.w;
            Vi[(k4 + 0) * 72 + r] = vi4.x; Vi[(k4 + 1) * 72 + r] = vi4.y;
            Vi[(k4 + 2) * 72 + r] = vi4.z; Vi[(k4 + 3) * 72 + r] = vi4.w;
        }
        __syncthreads();
        #pragma unroll
        for (int ks = 0; ks < 64; ks += 32) {
            f16x8 w1[2], w2[2], br[2], bi[2];
            #pragma unroll
            for (int i = 0; i < 2; ++i) {
                w1[i] = *(const f16x8*)&W1[(wm + i * 16 + fm) * 72 + ks + fq * 8];
                w2[i] = *(const f16x8*)&W2[(wm + i * 16 + fm) * 72 + ks + fq * 8];
                br[i] = *(const f16x8*)&Vr[(wn + i * 16 + fm) * 72 + ks + fq * 8];
                bi[i] = *(const f16x8*)&Vi[(wn + i * 16 + fm) * 72 + ks + fq * 8];
            }
            #pragma unroll
            for (int i = 0; i < 2; ++i)
                #pragma unroll
                for (int j = 0; j < 2; ++j) {
                    a1r[i][j] = __builtin_amdgcn_mfma_f32_16x16x32_f16(w1[i], br[j], a1r[i][j], 0, 0, 0);
                    a1i[i][j] = __builtin_amdgcn_mfma_f32_16x16x32_f16(w1[i], bi[j], a1i[i][j], 0, 0, 0);
                    a2r[i][j] = __builtin_amdgcn_mfma_f32_16x16x32_f16(w2[i], br[j], a2r[i][j], 0, 0, 0);
                    a2i[i][j] = __builtin_amdgcn_mfma_f32_16x16x32_f16(w2[i], bi[j], a2i[i][j], 0, 0, 0);
                }
        }
    }
    #pragma unroll
    for (int i = 0; i < 2; ++i)
        #pragma unroll
        for (int j = 0; j < 2; ++j) {
            int d = d0 + wn + j * 16 + fm;
            #pragma unroll
            for (int reg = 0; reg < 4; ++reg) {
                int q = q0 + wm + i * 16 + fq * 4 + reg;
                size_t rowb = (size_t)(h * S + q) * 256;
                acat_r[rowb + d]       = a1r[i][j][reg];
                acat_r[rowb + 128 + d] = a2r[i][j][reg];
                acat_i[rowb + d]       = a1i[i][j][reg];
                acat_i[rowb + 128 + d] = a2i[i][j][reg];
            }
        }
}

// ============================================================
// RMS over 256 complex + sub_w + (a1 - lam*a2) + complex gate (in place g).
// ============================================================
__global__ __launch_bounds__(256) void rmsgate_kernel(
    const float* __restrict__ acat_r, const float* __restrict__ acat_i,
    const float* __restrict__ sub_w, const float* __restrict__ lam_ptr,
    float* __restrict__ g_r, float* __restrict__ g_i)
{
    int row = blockIdx.x;
    int t = threadIdx.x;
    float ar = acat_r[(size_t)row * 256 + t];
    float ai = acat_i[(size_t)row * 256 + t];
    float ss = fmaf(ar, ar, ai * ai);
    #pragma unroll
    for (int off = 32; off; off >>= 1) ss += __shfl_xor(ss, off);
    __shared__ float red[4];
    if ((t & 63) == 0) red[t >> 6] = ss;
    __syncthreads();
    float total = red[0] + red[1] + red[2] + red[3];
    float inv_rms = 1.0f / sqrtf(total * (1.0f / 256.0f) + 1e-5f);
    float sw = sub_w[t];
    __shared__ float Cr[256], Ci[256];
    Cr[t] = ar * inv_rms * sw;
    Ci[t] = ai * inv_rms * sw;
    __syncthreads();
    if (t < 128) {
        float lam = lam_ptr[0];
        float o_r = Cr[t] - lam * Cr[t + 128];
        float o_i = Ci[t] - lam * Ci[t + 128];
        float gr = g_r[(size_t)row * 128 + t];
        float gi = g_i[(size_t)row * 128 + t];
        g_r[(size_t)row * 128 + t] = gr * o_r - gi * o_i;
        g_i[(size_t)row * 128 + t] = gr * o_i + gi * o_r;
    }
}

// ============================================================
extern "C" void kernel_launch(void* const* d_in, const int* in_sizes, int n_in,
                              void* d_out, int out_size, void* d_ws, size_t ws_size,
                              hipStream_t stream)
{
    (void)in_sizes; (void)n_in; (void)out_size;
    const float* q_r    = (const float*)d_in[0];
    const float* q_i    = (const float*)d_in[1];
    const float* k_r    = (const float*)d_in[2];
    const float* k_i    = (const float*)d_in[3];
    const float* v_r    = (const float*)d_in[4];
    const float* v_i    = (const float*)d_in[5];
    const float* pe_q_r = (const float*)d_in[6];
    const float* pe_q_i = (const float*)d_in[7];
    const float* pe_k_r = (const float*)d_in[8];
    const float* pe_k_i = (const float*)d_in[9];
    const float* qw_r   = (const float*)d_in[10];
    const float* qw_i   = (const float*)d_in[11];
    const float* qb_r   = (const float*)d_in[12];
    const float* qb_i   = (const float*)d_in[13];
    const float* kw_r   = (const float*)d_in[14];
    const float* kw_i   = (const float*)d_in[15];
    const float* kb_r   = (const float*)d_in[16];
    const float* kb_i   = (const float*)d_in[17];
    const float* vw_r   = (const float*)d_in[18];
    const float* vw_i   = (const float*)d_in[19];
    const float* vb_r   = (const float*)d_in[20];
    const float* vb_i   = (const float*)d_in[21];
    const float* gw_r   = (const float*)d_in[22];
    const float* gw_i   = (const float*)d_in[23];
    const float* gb_r   = (const float*)d_in[24];
    const float* gb_i   = (const float*)d_in[25];
    const float* ow_r   = (const float*)d_in[26];
    const float* ow_i   = (const float*)d_in[27];
    const float* ob_r   = (const float*)d_in[28];
    const float* ob_i   = (const float*)d_in[29];
    const float* lq1    = (const float*)d_in[30];
    const float* lk1    = (const float*)d_in[31];
    const float* lq2    = (const float*)d_in[32];
    const float* lk2    = (const float*)d_in[33];
    const float* sub_w  = (const float*)d_in[34];

    char* ws = (char*)d_ws;
    short* qp_r   = (short*)(ws + WS_QP_R);
    short* qp_i   = (short*)(ws + WS_QP_I);
    short* kp_r   = (short*)(ws + WS_KP_R);
    short* kp_i   = (short*)(ws + WS_KP_I);
    short* vp_r   = (short*)(ws + WS_VP_R);
    short* vp_i   = (short*)(ws + WS_VP_I);
    float* g_r    = (float*)(ws + WS_G_R);
    float* g_i    = (float*)(ws + WS_G_I);
    float* acat_r = (float*)(ws + WS_ACAT_R);
    float* acat_i = (float*)(ws + WS_ACAT_I);
    float* lam    = (float*)(ws + WS_LAM);

    float* out_r = (float*)d_out;
    float* out_i = out_r + (size_t)NROWS * D;

    // head-chunking by workspace (depends only on ws_size -> graph-safe)
    size_t avail = ws_size > WS_SC ? ws_size - WS_SC : 0;
    int nh_chunk = (int)(avail / (SC32_PER_HEAD + W16_PER_HEAD));
    if (nh_chunk < 1) nh_chunk = 1;
    if (nh_chunk > H) nh_chunk = H;
    float* sc32 = (float*)(ws + WS_SC);
    short* w16  = (short*)(ws + WS_SC + (size_t)nh_chunk * SC32_PER_HEAD);

    lam_kernel<<<1, 128, 0, stream>>>(lq1, lk1, lq2, lk2, lam);

    // projections (q/k/v -> fp16 with PE folded; g -> fp32)
    clin_mfma<true><<<dim3(192, 4), 256, 0, stream>>>(q_r, q_i, qw_r, qw_i, qb_r, qb_i,
                                                      pe_q_r, pe_q_i, qp_r, qp_i, 256);
    clin_mfma<true><<<dim3(192, 2), 256, 0, stream>>>(k_r, k_i, kw_r, kw_i, kb_r, kb_i,
                                                      pe_k_r, pe_k_i, kp_r, kp_i, 128);
    clin_mfma<true><<<dim3(192, 2), 256, 0, stream>>>(v_r, v_i, vw_r, vw_i, vb_r, vb_i,
                                                      nullptr, nullptr, vp_r, vp_i, 128);
    clin_mfma<false><<<dim3(192, 2), 256, 0, stream>>>(q_r, q_i, gw_r, gw_i, gb_r, gb_i,
                                                       nullptr, nullptr, g_r, g_i, 128);

    for (int h0 = 0; h0 < H; h0 += nh_chunk) {
        int nhh = (H - h0 < nh_chunk) ? (H - h0) : nh_chunk;
        score_mfma<<<dim3(16, 16, nhh), 256, 0, stream>>>(qp_r, qp_i, kp_r, kp_i, sc32, h0);
        softmax_f32_f16<<<nhh * 2 * S, 256, 0, stream>>>(sc32, w16);
        av_mfma<<<dim3(16, 2, nhh), 256, 0, stream>>>(w16, vp_r, vp_i, acat_r, acat_i, h0);
    }

    rmsgate_kernel<<<NROWS, 256, 0, stream>>>(acat_r, acat_i, sub_w, lam, g_r, g_i);

    clin_mfma<false><<<dim3(192, 2), 256, 0, stream>>>(g_r, g_i, ow_r, ow_i, ob_r, ob_i,
                                                       nullptr, nullptr, out_r, out_i, 128);
}

// Round 4
// 320.073 us; speedup vs baseline: 3.8793x; 1.1573x over previous
//
#include <hip/hip_runtime.h>
#include <math.h>

#define H 12
#define S 1024
#define D 128
#define NROWS (H * S) // 12288

typedef __attribute__((ext_vector_type(8))) _Float16 f16x8; // 8 fp16 in 4 VGPRs
typedef __attribute__((ext_vector_type(4))) float f32x4;
typedef __attribute__((ext_vector_type(4))) int i32x4;

__device__ __forceinline__ short f2h(float f) { // RNE float->fp16, bits as short
    _Float16 h = (_Float16)f;
    return __builtin_bit_cast(short, h);
}
__device__ __forceinline__ f16x8 fneg8(f16x8 v) { // packed sign flip
    i32x4 u = __builtin_bit_cast(i32x4, v);
    u ^= (int)0x80008000;
    return __builtin_bit_cast(f16x8, u);
}

// ---- workspace layout (BYTE offsets) ----
// qp fp16 [12288][256] r/i ; kp fp16 [12288][128] r/i ; vpT fp16 [H][128][1024] r/i
// g fp32 [12288][128] r/i ; acat fp32 [12288][256] r/i ; lam ; w16 fp16 per head 2*S*S
#define WS_QP_R   0ULL
#define WS_QP_I   6291456ULL
#define WS_KP_R   12582912ULL
#define WS_KP_I   15728640ULL
#define WS_VPT_R  18874368ULL
#define WS_VPT_I  22020096ULL
#define WS_G_R    25165824ULL
#define WS_G_I    31457280ULL
#define WS_ACAT_R 37748736ULL
#define WS_ACAT_I 50331648ULL
#define WS_LAM    62914560ULL
#define WS_SC     62914816ULL
#define W16_PER_HEAD  4194304ULL // 2*1024*1024*2B

// ============================================================
__global__ void lam_kernel(const float* __restrict__ lq1, const float* __restrict__ lk1,
                           const float* __restrict__ lq2, const float* __restrict__ lk2,
                           float* __restrict__ lam_out)
{
    int t = threadIdx.x; // 128 threads
    float p1 = lq1[t] * lk1[t];
    float p2 = lq2[t] * lk2[t];
    #pragma unroll
    for (int off = 32; off; off >>= 1) {
        p1 += __shfl_xor(p1, off);
        p2 += __shfl_xor(p2, off);
    }
    __shared__ float s1[2], s2[2];
    if ((t & 63) == 0) { s1[t >> 6] = p1; s2[t >> 6] = p2; }
    __syncthreads();
    if (t == 0) {
        float l1 = expf(s1[0] + s1[1]);
        float l2 = expf(s2[0] + s2[1]);
        float x = l1 - l2 + 0.3555090675909693f; // 0.8 - 0.6*exp(-0.3)
        lam_out[0] = 1.0f / (1.0f + expf(-x));
    }
}

// ============================================================
// Complex linear via fp16 MFMA, K-concat over 256 virtual K:
//   out_r = [xr,xi] . [wr,-wi]^T ; out_i = [xr,xi] . [wi,wr]^T
// OMODE: 0 = fp32 [row][M], 1 = fp16 [row][M], 2 = fp16 transposed [h][col][s]
// ============================================================
template <int OMODE>
__global__ __launch_bounds__(256) void clin_mfma(
    const float* __restrict__ xr, const float* __restrict__ xi,
    const float* __restrict__ wr, const float* __restrict__ wi,
    const float* __restrict__ br, const float* __restrict__ bi,
    const float* __restrict__ per, const float* __restrict__ pei,
    void* __restrict__ outr_, void* __restrict__ outi_, int M)
{
    __shared__ short As[64 * 72], Brs[64 * 72], Bis[64 * 72];
    const int t = threadIdx.x;
    const int row0 = blockIdx.x * 64, col0 = blockIdx.y * 64;
    const int lane = t & 63, wid = t >> 6;
    const int wm = (wid >> 1) * 32, wn = (wid & 1) * 32;
    const int fm = lane & 15, fq = lane >> 4;
    f32x4 zero4 = {0.f, 0.f, 0.f, 0.f};
    f32x4 accr[2][2], acci[2][2];
    #pragma unroll
    for (int i = 0; i < 2; ++i)
        #pragma unroll
        for (int j = 0; j < 2; ++j) { accr[i][j] = zero4; acci[i][j] = zero4; }

    for (int c = 0; c < 4; ++c) {
        const bool hi = (c >= 2);
        const int kb = (c & 1) * 64;
        const float* Asrc = hi ? xi : xr;
        const float* Brsrc = hi ? wi : wr;
        const float* Bisrc = hi ? wr : wi;
        const float bsign = hi ? -1.0f : 1.0f;
        __syncthreads();
        #pragma unroll
        for (int i = 0; i < 4; ++i) {
            int lin = i * 256 + t;
            int r = lin >> 4;
            int k4 = (lin & 15) * 4;
            float4 va = *(const float4*)&Asrc[(size_t)(row0 + r) * 128 + kb + k4];
            *(short4*)&As[r * 72 + k4] = make_short4(f2h(va.x), f2h(va.y), f2h(va.z), f2h(va.w));
            float4 vr = *(const float4*)&Brsrc[(size_t)(col0 + r) * 128 + kb + k4];
            *(short4*)&Brs[r * 72 + k4] = make_short4(f2h(bsign * vr.x), f2h(bsign * vr.y),
                                                      f2h(bsign * vr.z), f2h(bsign * vr.w));
            float4 vi = *(const float4*)&Bisrc[(size_t)(col0 + r) * 128 + kb + k4];
            *(short4*)&Bis[r * 72 + k4] = make_short4(f2h(vi.x), f2h(vi.y), f2h(vi.z), f2h(vi.w));
        }
        __syncthreads();
        #pragma unroll
        for (int ks = 0; ks < 64; ks += 32) {
            f16x8 a[2], bfr[2], bfi[2];
            #pragma unroll
            for (int i = 0; i < 2; ++i) {
                a[i]   = *(const f16x8*)&As[(wm + i * 16 + fm) * 72 + ks + fq * 8];
                bfr[i] = *(const f16x8*)&Brs[(wn + i * 16 + fm) * 72 + ks + fq * 8];
                bfi[i] = *(const f16x8*)&Bis[(wn + i * 16 + fm) * 72 + ks + fq * 8];
            }
            #pragma unroll
            for (int i = 0; i < 2; ++i)
                #pragma unroll
                for (int j = 0; j < 2; ++j) {
                    accr[i][j] = __builtin_amdgcn_mfma_f32_16x16x32_f16(a[i], bfr[j], accr[i][j], 0, 0, 0);
                    acci[i][j] = __builtin_amdgcn_mfma_f32_16x16x32_f16(a[i], bfi[j], acci[i][j], 0, 0, 0);
                }
        }
    }
    #pragma unroll
    for (int i = 0; i < 2; ++i)
        #pragma unroll
        for (int j = 0; j < 2; ++j) {
            int colc = col0 + wn + j * 16 + fm;
            float bbr = br[colc], bbi = bi[colc];
            if (OMODE == 2) {
                // transposed fp16 store: out[h][colc][s], 4 consecutive s per short4
                int rb = row0 + wm + i * 16 + fq * 4;
                int hq = rb >> 10, sq = rb & 1023;
                short4 o_r4, o_i4;
                float r0 = accr[i][j][0] + bbr, r1 = accr[i][j][1] + bbr;
                float r2 = accr[i][j][2] + bbr, r3 = accr[i][j][3] + bbr;
                float i0 = acci[i][j][0] + bbi, i1 = acci[i][j][1] + bbi;
                float i2v = acci[i][j][2] + bbi, i3 = acci[i][j][3] + bbi;
                o_r4 = make_short4(f2h(r0), f2h(r1), f2h(r2), f2h(r3));
                o_i4 = make_short4(f2h(i0), f2h(i1), f2h(i2v), f2h(i3));
                size_t ob = ((size_t)(hq * 128 + colc)) * 1024 + sq;
                *(short4*)&((short*)outr_)[ob] = o_r4;
                *(short4*)&((short*)outi_)[ob] = o_i4;
            } else {
                #pragma unroll
                for (int reg = 0; reg < 4; ++reg) {
                    int rr = row0 + wm + i * 16 + fq * 4 + reg;
                    float o_r = accr[i][j][reg] + bbr;
                    float o_i = acci[i][j][reg] + bbi;
                    if (per) {
                        o_r += per[(size_t)rr * 128 + (colc & 127)];
                        o_i += pei[(size_t)rr * 128 + (colc & 127)];
                    }
                    if (OMODE == 1) {
                        ((short*)outr_)[(size_t)rr * M + colc] = f2h(o_r);
                        ((short*)outi_)[(size_t)rr * M + colc] = f2h(o_i);
                    } else {
                        ((float*)outr_)[(size_t)rr * M + colc] = o_r;
                        ((float*)outi_)[(size_t)rr * M + colc] = o_i;
                    }
                }
            }
        }
}

// ============================================================
// Scores v2: one map per block, 64q x 128k tile, K-chunk 64.
// A-fragments (q_r, q_i) held in regs across two B-phases (kr, then ki):
//   phase1: sr += qr.kr ; si += qi.kr
//   phase2: sr += qi.ki ; si += (-qr).ki
// mag = sqrt(sr^2+si^2+1e-8)*D^-.5 -> fp16 w16[(hh*2+map)*S+q][k]
// ============================================================
__global__ __launch_bounds__(256) void score_mfma(
    const short* __restrict__ qp_r, const short* __restrict__ qp_i,
    const short* __restrict__ kp_r, const short* __restrict__ kp_i,
    short* __restrict__ w16, int h0)
{
    __shared__ short Qr[64 * 72], Qi[64 * 72], Kt[128 * 72];
    const int t = threadIdx.x;
    const int hh = blockIdx.z >> 1, map = blockIdx.z & 1;
    const int h = h0 + hh;
    const int q0 = blockIdx.x * 64, c0 = blockIdx.y * 128;
    const int lane = t & 63, wid = t >> 6;
    const int wm = (wid >> 1) * 32, wn = (wid & 1) * 64;
    const int fm = lane & 15, fq = lane >> 4;
    f32x4 zero4 = {0.f, 0.f, 0.f, 0.f};
    f32x4 sr[2][4], si[2][4];
    #pragma unroll
    for (int i = 0; i < 2; ++i)
        #pragma unroll
        for (int j = 0; j < 4; ++j) { sr[i][j] = zero4; si[i][j] = zero4; }

    for (int kb = 0; kb < 2; ++kb) {
        const int kbase = map * 128 + kb * 64;
        __syncthreads();
        // stage Qr, Qi (64x64) and Kt = kr (128x64)
        #pragma unroll
        for (int i = 0; i < 4; ++i) {
            int lin = i * 256 + t;
            int r = lin >> 4, k4 = (lin & 15) * 4;
            size_t qb = (size_t)(h * S + q0 + r) * 256 + kbase + k4;
            *(short4*)&Qr[r * 72 + k4] = *(const short4*)&qp_r[qb];
            *(short4*)&Qi[r * 72 + k4] = *(const short4*)&qp_i[qb];
        }
        #pragma unroll
        for (int i = 0; i < 8; ++i) {
            int lin = i * 256 + t;
            int r = lin >> 4, k4 = (lin & 15) * 4;
            *(short4*)&Kt[r * 72 + k4] =
                *(const short4*)&kp_r[(size_t)(h * S + c0 + r) * 128 + kb * 64 + k4];
        }
        __syncthreads();
        // load A fragments (held across both phases)
        f16x8 aR[2][2], aI[2][2]; // [ks][i]
        #pragma unroll
        for (int ks = 0; ks < 2; ++ks)
            #pragma unroll
            for (int i = 0; i < 2; ++i) {
                int ao = (wm + i * 16 + fm) * 72 + ks * 32 + fq * 8;
                aR[ks][i] = *(const f16x8*)&Qr[ao];
                aI[ks][i] = *(const f16x8*)&Qi[ao];
            }
        // phase 1: B = kr
        #pragma unroll
        for (int ks = 0; ks < 2; ++ks) {
            f16x8 b[4];
            #pragma unroll
            for (int j = 0; j < 4; ++j)
                b[j] = *(const f16x8*)&Kt[(wn + j * 16 + fm) * 72 + ks * 32 + fq * 8];
            #pragma unroll
            for (int i = 0; i < 2; ++i)
                #pragma unroll
                for (int j = 0; j < 4; ++j) {
                    sr[i][j] = __builtin_amdgcn_mfma_f32_16x16x32_f16(aR[ks][i], b[j], sr[i][j], 0, 0, 0);
                    si[i][j] = __builtin_amdgcn_mfma_f32_16x16x32_f16(aI[ks][i], b[j], si[i][j], 0, 0, 0);
                }
        }
        __syncthreads();
        // restage Kt = ki
        #pragma unroll
        for (int i = 0; i < 8; ++i) {
            int lin = i * 256 + t;
            int r = lin >> 4, k4 = (lin & 15) * 4;
            *(short4*)&Kt[r * 72 + k4] =
                *(const short4*)&kp_i[(size_t)(h * S + c0 + r) * 128 + kb * 64 + k4];
        }
        __syncthreads();
        // phase 2: B = ki ; sr += qi.ki, si += (-qr).ki
        #pragma unroll
        for (int ks = 0; ks < 2; ++ks) {
            f16x8 b[4];
            #pragma unroll
            for (int j = 0; j < 4; ++j)
                b[j] = *(const f16x8*)&Kt[(wn + j * 16 + fm) * 72 + ks * 32 + fq * 8];
            f16x8 nR0 = fneg8(aR[ks][0]), nR1 = fneg8(aR[ks][1]);
            #pragma unroll
            for (int j = 0; j < 4; ++j) {
                sr[0][j] = __builtin_amdgcn_mfma_f32_16x16x32_f16(aI[ks][0], b[j], sr[0][j], 0, 0, 0);
                si[0][j] = __builtin_amdgcn_mfma_f32_16x16x32_f16(nR0, b[j], si[0][j], 0, 0, 0);
                sr[1][j] = __builtin_amdgcn_mfma_f32_16x16x32_f16(aI[ks][1], b[j], sr[1][j], 0, 0, 0);
                si[1][j] = __builtin_amdgcn_mfma_f32_16x16x32_f16(nR1, b[j], si[1][j], 0, 0, 0);
            }
        }
    }
    const float scale = 0.08838834764831845f;
    #pragma unroll
    for (int i = 0; i < 2; ++i)
        #pragma unroll
        for (int j = 0; j < 4; ++j) {
            int kcol = c0 + wn + j * 16 + fm;
            #pragma unroll
            for (int reg = 0; reg < 4; ++reg) {
                int q = q0 + wm + i * 16 + fq * 4 + reg;
                float r1 = sr[i][j][reg], I1 = si[i][j][reg];
                float m1 = sqrtf(fmaf(r1, r1, fmaf(I1, I1, 1e-8f))) * scale;
                w16[(((size_t)hh * 2 + map) * S + q) * S + kcol] = f2h(m1);
            }
        }
}

// ============================================================
// Row softmax over 1024, fp16 in/out in place, fp32 math. One block/row.
// ============================================================
__global__ __launch_bounds__(256) void softmax_f16(short* __restrict__ w16)
{
    short* row = w16 + (size_t)blockIdx.x * S;
    int t = threadIdx.x;
    short4 s = ((short4*)row)[t];
    float f0 = (float)__builtin_bit_cast(_Float16, s.x);
    float f1 = (float)__builtin_bit_cast(_Float16, s.y);
    float f2v = (float)__builtin_bit_cast(_Float16, s.z);
    float f3 = (float)__builtin_bit_cast(_Float16, s.w);
    float m = fmaxf(fmaxf(f0, f1), fmaxf(f2v, f3));
    #pragma unroll
    for (int off = 32; off; off >>= 1) m = fmaxf(m, __shfl_xor(m, off));
    __shared__ float redm[4], reds[4];
    int w = t >> 6;
    if ((t & 63) == 0) redm[w] = m;
    __syncthreads();
    m = fmaxf(fmaxf(redm[0], redm[1]), fmaxf(redm[2], redm[3]));
    float e0 = __expf(f0 - m), e1 = __expf(f1 - m), e2 = __expf(f2v - m), e3 = __expf(f3 - m);
    float ssum = e0 + e1 + e2 + e3;
    #pragma unroll
    for (int off = 32; off; off >>= 1) ssum += __shfl_xor(ssum, off);
    if ((t & 63) == 0) reds[w] = ssum;
    __syncthreads();
    ssum = reds[0] + reds[1] + reds[2] + reds[3];
    float inv = 1.0f / ssum;
    s.x = f2h(e0 * inv); s.y = f2h(e1 * inv); s.z = f2h(e2 * inv); s.w = f2h(e3 * inv);
    ((short4*)row)[t] = s;
}

// ============================================================
// AV via fp16 MFMA. V read from transposed layout vpT[h][d][s] -> vector staging.
// ============================================================
__global__ __launch_bounds__(256) void av_mfma(
    const short* __restrict__ w16, const short* __restrict__ vpT_r, const short* __restrict__ vpT_i,
    float* __restrict__ acat_r, float* __restrict__ acat_i, int h0)
{
    __shared__ short W1[64 * 72], W2[64 * 72], Vr[64 * 72], Vi[64 * 72];
    const int t = threadIdx.x;
    const int hh = blockIdx.z, h = h0 + hh;
    const int q0 = blockIdx.x * 64, d0 = blockIdx.y * 64;
    const int lane = t & 63, wid = t >> 6;
    const int wm = (wid >> 1) * 32, wn = (wid & 1) * 32;
    const int fm = lane & 15, fq = lane >> 4;
    f32x4 zero4 = {0.f, 0.f, 0.f, 0.f};
    f32x4 a1r[2][2], a1i[2][2], a2r[2][2], a2i[2][2];
    #pragma unroll
    for (int i = 0; i < 2; ++i)
        #pragma unroll
        for (int j = 0; j < 2; ++j) { a1r[i][j] = zero4; a1i[i][j] = zero4; a2r[i][j] = zero4; a2i[i][j] = zero4; }

    for (int k0 = 0; k0 < S; k0 += 64) {
        __syncthreads();
        #pragma unroll
        for (int i = 0; i < 4; ++i) {
            int lin = i * 256 + t;
            int r = lin >> 4, k4 = (lin & 15) * 4;
            *(short4*)&W1[r * 72 + k4] = *(const short4*)&w16[(((size_t)hh * 2 + 0) * S + q0 + r) * S + k0 + k4];
            *(short4*)&W2[r * 72 + k4] = *(const short4*)&w16[(((size_t)hh * 2 + 1) * S + q0 + r) * S + k0 + k4];
            // V tiles from transposed layout: row r = d-offset, cols = k-chunk
            size_t vb = (size_t)(h * 128 + d0 + r) * 1024 + k0 + k4;
            *(short4*)&Vr[r * 72 + k4] = *(const short4*)&vpT_r[vb];
            *(short4*)&Vi[r * 72 + k4] = *(const short4*)&vpT_i[vb];
        }
        __syncthreads();
        #pragma unroll
        for (int ks = 0; ks < 64; ks += 32) {
            f16x8 w1[2], w2[2], br[2], bi[2];
            #pragma unroll
            for (int i = 0; i < 2; ++i) {
                w1[i] = *(const f16x8*)&W1[(wm + i * 16 + fm) * 72 + ks + fq * 8];
                w2[i] = *(const f16x8*)&W2[(wm + i * 16 + fm) * 72 + ks + fq * 8];
                br[i] = *(const f16x8*)&Vr[(wn + i * 16 + fm) * 72 + ks + fq * 8];
                bi[i] = *(const f16x8*)&Vi[(wn + i * 16 + fm) * 72 + ks + fq * 8];
            }
            #pragma unroll
            for (int i = 0; i < 2; ++i)
                #pragma unroll
                for (int j = 0; j < 2; ++j) {
                    a1r[i][j] = __builtin_amdgcn_mfma_f32_16x16x32_f16(w1[i], br[j], a1r[i][j], 0, 0, 0);
                    a1i[i][j] = __builtin_amdgcn_mfma_f32_16x16x32_f16(w1[i], bi[j], a1i[i][j], 0, 0, 0);
                    a2r[i][j] = __builtin_amdgcn_mfma_f32_16x16x32_f16(w2[i], br[j], a2r[i][j], 0, 0, 0);
                    a2i[i][j] = __builtin_amdgcn_mfma_f32_16x16x32_f16(w2[i], bi[j], a2i[i][j], 0, 0, 0);
                }
        }
    }
    #pragma unroll
    for (int i = 0; i < 2; ++i)
        #pragma unroll
        for (int j = 0; j < 2; ++j) {
            int d = d0 + wn + j * 16 + fm;
            #pragma unroll
            for (int reg = 0; reg < 4; ++reg) {
                int q = q0 + wm + i * 16 + fq * 4 + reg;
                size_t rowb = (size_t)(h * S + q) * 256;
                acat_r[rowb + d]       = a1r[i][j][reg];
                acat_r[rowb + 128 + d] = a2r[i][j][reg];
                acat_i[rowb + d]       = a1i[i][j][reg];
                acat_i[rowb + 128 + d] = a2i[i][j][reg];
            }
        }
}

// ============================================================
// RMS over 256 complex + sub_w + (a1 - lam*a2) + complex gate (in place g).
// ============================================================
__global__ __launch_bounds__(256) void rmsgate_kernel(
    const float* __restrict__ acat_r, const float* __restrict__ acat_i,
    const float* __restrict__ sub_w, const float* __restrict__ lam_ptr,
    float* __restrict__ g_r, float* __restrict__ g_i)
{
    int row = blockIdx.x;
    int t = threadIdx.x;
    float ar = acat_r[(size_t)row * 256 + t];
    float ai = acat_i[(size_t)row * 256 + t];
    float ss = fmaf(ar, ar, ai * ai);
    #pragma unroll
    for (int off = 32; off; off >>= 1) ss += __shfl_xor(ss, off);
    __shared__ float red[4];
    if ((t & 63) == 0) red[t >> 6] = ss;
    __syncthreads();
    float total = red[0] + red[1] + red[2] + red[3];
    float inv_rms = 1.0f / sqrtf(total * (1.0f / 256.0f) + 1e-5f);
    float sw = sub_w[t];
    __shared__ float Cr[256], Ci[256];
    Cr[t] = ar * inv_rms * sw;
    Ci[t] = ai * inv_rms * sw;
    __syncthreads();
    if (t < 128) {
        float lam = lam_ptr[0];
        float o_r = Cr[t] - lam * Cr[t + 128];
        float o_i = Ci[t] - lam * Ci[t + 128];
        float gr = g_r[(size_t)row * 128 + t];
        float gi = g_i[(size_t)row * 128 + t];
        g_r[(size_t)row * 128 + t] = gr * o_r - gi * o_i;
        g_i[(size_t)row * 128 + t] = gr * o_i + gi * o_r;
    }
}

// ============================================================
extern "C" void kernel_launch(void* const* d_in, const int* in_sizes, int n_in,
                              void* d_out, int out_size, void* d_ws, size_t ws_size,
                              hipStream_t stream)
{
    (void)in_sizes; (void)n_in; (void)out_size;
    const float* q_r    = (const float*)d_in[0];
    const float* q_i    = (const float*)d_in[1];
    const float* k_r    = (const float*)d_in[2];
    const float* k_i    = (const float*)d_in[3];
    const float* v_r    = (const float*)d_in[4];
    const float* v_i    = (const float*)d_in[5];
    const float* pe_q_r = (const float*)d_in[6];
    const float* pe_q_i = (const float*)d_in[7];
    const float* pe_k_r = (const float*)d_in[8];
    const float* pe_k_i = (const float*)d_in[9];
    const float* qw_r   = (const float*)d_in[10];
    const float* qw_i   = (const float*)d_in[11];
    const float* qb_r   = (const float*)d_in[12];
    const float* qb_i   = (const float*)d_in[13];
    const float* kw_r   = (const float*)d_in[14];
    const float* kw_i   = (const float*)d_in[15];
    const float* kb_r   = (const float*)d_in[16];
    const float* kb_i   = (const float*)d_in[17];
    const float* vw_r   = (const float*)d_in[18];
    const float* vw_i   = (const float*)d_in[19];
    const float* vb_r   = (const float*)d_in[20];
    const float* vb_i   = (const float*)d_in[21];
    const float* gw_r   = (const float*)d_in[22];
    const float* gw_i   = (const float*)d_in[23];
    const float* gb_r   = (const float*)d_in[24];
    const float* gb_i   = (const float*)d_in[25];
    const float* ow_r   = (const float*)d_in[26];
    const float* ow_i   = (const float*)d_in[27];
    const float* ob_r   = (const float*)d_in[28];
    const float* ob_i   = (const float*)d_in[29];
    const float* lq1    = (const float*)d_in[30];
    const float* lk1    = (const float*)d_in[31];
    const float* lq2    = (const float*)d_in[32];
    const float* lk2    = (const float*)d_in[33];
    const float* sub_w  = (const float*)d_in[34];

    char* ws = (char*)d_ws;
    short* qp_r   = (short*)(ws + WS_QP_R);
    short* qp_i   = (short*)(ws + WS_QP_I);
    short* kp_r   = (short*)(ws + WS_KP_R);
    short* kp_i   = (short*)(ws + WS_KP_I);
    short* vpT_r  = (short*)(ws + WS_VPT_R);
    short* vpT_i  = (short*)(ws + WS_VPT_I);
    float* g_r    = (float*)(ws + WS_G_R);
    float* g_i    = (float*)(ws + WS_G_I);
    float* acat_r = (float*)(ws + WS_ACAT_R);
    float* acat_i = (float*)(ws + WS_ACAT_I);
    float* lam    = (float*)(ws + WS_LAM);
    short* w16    = (short*)(ws + WS_SC);

    float* out_r = (float*)d_out;
    float* out_i = out_r + (size_t)NROWS * D;

    // head-chunking by workspace (depends only on ws_size -> graph-safe)
    size_t avail = ws_size > WS_SC ? ws_size - WS_SC : 0;
    int nh_chunk = (int)(avail / W16_PER_HEAD);
    if (nh_chunk < 1) nh_chunk = 1;
    if (nh_chunk > H) nh_chunk = H;

    lam_kernel<<<1, 128, 0, stream>>>(lq1, lk1, lq2, lk2, lam);

    // projections (q/k -> fp16 with PE folded; v -> fp16 transposed; g -> fp32)
    clin_mfma<1><<<dim3(192, 4), 256, 0, stream>>>(q_r, q_i, qw_r, qw_i, qb_r, qb_i,
                                                   pe_q_r, pe_q_i, qp_r, qp_i, 256);
    clin_mfma<1><<<dim3(192, 2), 256, 0, stream>>>(k_r, k_i, kw_r, kw_i, kb_r, kb_i,
                                                   pe_k_r, pe_k_i, kp_r, kp_i, 128);
    clin_mfma<2><<<dim3(192, 2), 256, 0, stream>>>(v_r, v_i, vw_r, vw_i, vb_r, vb_i,
                                                   nullptr, nullptr, vpT_r, vpT_i, 128);
    clin_mfma<0><<<dim3(192, 2), 256, 0, stream>>>(q_r, q_i, gw_r, gw_i, gb_r, gb_i,
                                                   nullptr, nullptr, g_r, g_i, 128);

    for (int h0 = 0; h0 < H; h0 += nh_chunk) {
        int nhh = (H - h0 < nh_chunk) ? (H - h0) : nh_chunk;
        score_mfma<<<dim3(16, 8, nhh * 2), 256, 0, stream>>>(qp_r, qp_i, kp_r, kp_i, w16, h0);
        softmax_f16<<<nhh * 2 * S, 256, 0, stream>>>(w16);
        av_mfma<<<dim3(16, 2, nhh), 256, 0, stream>>>(w16, vpT_r, vpT_i, acat_r, acat_i, h0);
    }

    rmsgate_kernel<<<NROWS, 256, 0, stream>>>(acat_r, acat_i, sub_w, lam, g_r, g_i);

    clin_mfma<0><<<dim3(192, 2), 256, 0, stream>>>(g_r, g_i, ow_r, ow_i, ob_r, ob_i,
                                                   nullptr, nullptr, out_r, out_i, 128);
}